// Round 17
// baseline (100.058 us; speedup 1.0000x reference)
//
#include <hip/hip_runtime.h>
#include <hip/hip_cooperative_groups.h>
#include <hip/hip_bf16.h>
#include <math.h>

#define NB 1024
#define N 256
#define NBN (NB * N)
#define EPS 1e-6f
#define SQRT_EPS 1e-3f   // sqrt(1e-6)

namespace cg = cooperative_groups;

typedef short bf16x8 __attribute__((ext_vector_type(8)));
typedef float f32x4  __attribute__((ext_vector_type(4)));

__device__ __forceinline__ float fast_rcp(float x) {
    return __builtin_amdgcn_rcpf(x);
}
__device__ __forceinline__ float sigmoidf(float x) {
    return fast_rcp(1.0f + __expf(-x));
}
__device__ __forceinline__ float fast_tanh(float x) {
    float ax = fabsf(x);
    float e  = __expf(2.0f * ax);
    float t  = 1.0f - 2.0f * fast_rcp(e + 1.0f);
    return copysignf(t, x);
}
__device__ __forceinline__ unsigned short to_bf16(float f) {
    __hip_bfloat16 h = __float2bfloat16(f);
    return *(unsigned short*)&h;
}
__device__ __forceinline__ bf16x8 cvt8(float4 f0, float4 f1) {
    bf16x8 a;
    a[0] = (short)to_bf16(f0.x); a[1] = (short)to_bf16(f0.y);
    a[2] = (short)to_bf16(f0.z); a[3] = (short)to_bf16(f0.w);
    a[4] = (short)to_bf16(f1.x); a[5] = (short)to_bf16(f1.y);
    a[6] = (short)to_bf16(f1.z); a[7] = (short)to_bf16(f1.w);
    return a;
}

// ---- cooperative fused MLP: 256 blocks x 768 threads (12 waves).
// Block: row-tile rt = blk>>2 (16 batch rows), col-tile ct = blk&3 (64
// neurons). Wave w: mlp = w>>2, 16-neuron subtile = w&3. A-frags staged
// ONCE in LDS (bf16) per phase (kills 12x redundant global loads + cvt).
// grid.sync() between layers (h1 crosses the 4-block col-tile group).
// mfma_f32_16x16x32_bf16 frags (verified R12-R16, absmax 0.031):
//   A/B: lane idx = lane&15, k = (lane>>4)*8 + e
//   C/D: col = lane&15 (neuron), row = (lane>>4)*4 + reg (batch row)
__global__ __launch_bounds__(768) void coop_mlp_kernel(
    const float* __restrict__ x,
    const float* __restrict__ Wd1, const float* __restrict__ Wu1,
    const float* __restrict__ Wm1,
    const float* __restrict__ Wd2, const float* __restrict__ Wu2,
    const float* __restrict__ Wm2,
    const float* __restrict__ bd1, const float* __restrict__ bu1,
    const float* __restrict__ bm1,
    const float* __restrict__ bd2, const float* __restrict__ bu2,
    const float* __restrict__ bm2,
    unsigned short* __restrict__ h1g, float* __restrict__ h2g)
{
    __shared__ unsigned short xa[16][264];      // 8.4 KB staged x (bf16)
    __shared__ unsigned short hb[3][16][264];   // 25.3 KB staged h1 (bf16)

    const int tid = threadIdx.x;
    const int w   = tid >> 6;          // 0..11
    const int mlp = w >> 2;            // 0..2
    const int sub = w & 3;             // 0..3
    const int l   = tid & 63;
    const int ml  = l & 15;
    const int kg  = l >> 4;
    const int b0  = ((int)blockIdx.x >> 2) * 16;
    const int n0  = ((int)blockIdx.x & 3) * 64 + sub * 16;
    const int n   = n0 + ml;

    // ---- stage x rows -> LDS bf16 (512 threads, one bf16x8 each) ----
    if (tid < 512) {
        const int row = tid >> 5;
        const int c8  = tid & 31;
        const float* src = x + (size_t)(b0 + row) * N + c8 * 8;
        float4 f0 = *(const float4*)src;
        float4 f1 = *(const float4*)(src + 4);
        *(bf16x8*)&xa[row][c8 * 8] = cvt8(f0, f1);
    }
    __syncthreads();

    // ---- layer 1 ----
    {
        bf16x8 af[8];
        #pragma unroll
        for (int kq = 0; kq < 8; ++kq)
            af[kq] = *(const bf16x8*)&xa[ml][kq * 32 + kg * 8];
        const float* Wl = (mlp == 0) ? Wd1 : (mlp == 1) ? Wu1 : Wm1;
        const float* wrow = Wl + (size_t)n * N;
        f32x4 acc = {0.f, 0.f, 0.f, 0.f};
        #pragma unroll
        for (int kq = 0; kq < 8; ++kq) {
            float4 f0 = *(const float4*)(wrow + kq * 32 + kg * 8);
            float4 f1 = *(const float4*)(wrow + kq * 32 + kg * 8 + 4);
            acc = __builtin_amdgcn_mfma_f32_16x16x32_bf16(af[kq], cvt8(f0, f1), acc, 0, 0, 0);
        }
        const float* bias = (mlp == 0) ? bd1 : (mlp == 1) ? bu1 : bm1;
        const float bb = bias[n];
        #pragma unroll
        for (int reg = 0; reg < 4; ++reg) {
            const int row = b0 + kg * 4 + reg;
            float val = acc[reg] + bb;
            float act = (mlp < 2) ? sigmoidf(val) : fast_tanh(val);
            h1g[(size_t)mlp * NBN + (size_t)row * N + n] = to_bf16(act);
        }
    }

    cg::this_grid().sync();

    // ---- stage h1 rows (3 mlps x 16 rows x 256 n) -> LDS ----
    #pragma unroll
    for (int t = 0; t < 2; ++t) {
        const int idx = tid * 2 + t;         // 0..1535
        const int m2  = idx >> 9;            // mlp plane
        const int rem = idx & 511;
        const int row = rem >> 5;
        const int c8  = rem & 31;
        *(bf16x8*)&hb[m2][row][c8 * 8] =
            *(const bf16x8*)(h1g + (size_t)m2 * NBN + (size_t)(b0 + row) * N + c8 * 8);
    }
    __syncthreads();

    // ---- layer 2 ----
    {
        bf16x8 af[8];
        #pragma unroll
        for (int kq = 0; kq < 8; ++kq)
            af[kq] = *(const bf16x8*)&hb[mlp][ml][kq * 32 + kg * 8];
        const float* Wl = (mlp == 0) ? Wd2 : (mlp == 1) ? Wu2 : Wm2;
        const float* wrow = Wl + (size_t)n * N;
        f32x4 acc = {0.f, 0.f, 0.f, 0.f};
        #pragma unroll
        for (int kq = 0; kq < 8; ++kq) {
            float4 f0 = *(const float4*)(wrow + kq * 32 + kg * 8);
            float4 f1 = *(const float4*)(wrow + kq * 32 + kg * 8 + 4);
            acc = __builtin_amdgcn_mfma_f32_16x16x32_bf16(af[kq], cvt8(f0, f1), acc, 0, 0, 0);
        }
        const float* bias = (mlp == 0) ? bd2 : (mlp == 1) ? bu2 : bm2;
        const float bb = bias[n];
        #pragma unroll
        for (int reg = 0; reg < 4; ++reg) {
            const int row = b0 + kg * 4 + reg;
            float val = acc[reg] + bb;
            float act = (mlp < 2) ? sigmoidf(val) : fast_tanh(val);
            h2g[(size_t)mlp * NBN + (size_t)row * N + n] = act;
        }
    }
}

// ---- R writer with fused epilogue (BYTE-IDENTICAL to R16's r_epi_kernel).
__global__ __launch_bounds__(256) void r_epi_kernel(
    const float* __restrict__ h2g, const float* __restrict__ v,
    float* __restrict__ out_mean, float* __restrict__ out_z,
    float* __restrict__ R)
{
    __shared__ float s_lds[N];
    __shared__ float a_lds[64];
    __shared__ float tp_lds[64];
    __shared__ float red1[4][3];
    __shared__ float red2[4];

    const int tid   = threadIdx.x;
    const int b     = blockIdx.x >> 2;
    const int chunk = blockIdx.x & 3;
    const int ibase = chunk * 64;
    const int lane  = tid & 63;
    const int wv    = tid >> 6;

    const float d_ = h2g[(size_t)0 * NBN + (size_t)b * N + tid];
    const float u_ = h2g[(size_t)1 * NBN + (size_t)b * N + tid];
    const float m_ = h2g[(size_t)2 * NBN + (size_t)b * N + tid];
    const float vv = v[(size_t)b * N + tid];
    const float inv_d = fast_rcp(d_);

    float s0 = u_, s1 = u_ * u_ * inv_d, s2 = vv;
    #pragma unroll
    for (int off = 32; off > 0; off >>= 1) {
        s0 += __shfl_down(s0, off, 64);
        s1 += __shfl_down(s1, off, 64);
        s2 += __shfl_down(s2, off, 64);
    }
    if (lane == 0) { red1[wv][0] = s0; red1[wv][1] = s1; red1[wv][2] = s2; }
    __syncthreads();
    const float Su = red1[0][0] + red1[1][0] + red1[2][0] + red1[3][0];
    const float qs = red1[0][1] + red1[1][1] + red1[2][1] + red1[3][1];
    const float Sv = red1[0][2] + red1[1][2] + red1[2][2] + red1[3][2];
    const float utDu  = qs + EPS * Su * Su;
    const float sqeta = rsqrtf(1.0f + utDu);
    const float right = (1.0f - sqeta) / utDu;
    const float a  = sqrtf(inv_d + EPS);
    const float s  = u_ * a + SQRT_EPS * (Su - u_);
    const float tp = right * (u_ * inv_d + EPS * Su);

    float sv = s * vv;
    #pragma unroll
    for (int off = 32; off > 0; off >>= 1)
        sv += __shfl_down(sv, off, 64);
    if (lane == 0) red2[wv] = sv;

    s_lds[tid] = s;
    if (tid >= ibase && tid < ibase + 64) {
        a_lds[tid - ibase]  = a;
        tp_lds[tid - ibase] = tp;
    }
    __syncthreads();
    sv = red2[0] + red2[1] + red2[2] + red2[3];

    if (chunk == 0) {
        const size_t idx = (size_t)b * N + tid;
        out_mean[idx] = m_;
        out_z[idx]    = SQRT_EPS * Sv + (a - SQRT_EPS) * vv - tp * sv + m_;
    }

    const int j4 = tid & 63;
    const int il = tid >> 6;
    const float4 svec = ((const float4*)s_lds)[j4];
    float4* Rb = (float4*)(R + (size_t)b * N * N);
    const int jb = j4 * 4;

    #pragma unroll
    for (int it = 0; it < 16; ++it) {
        const int i_loc = it * 4 + il;
        const int i     = ibase + i_loc;
        const float ai  = a_lds[i_loc];
        const float ti  = tp_lds[i_loc];
        float4 o;
        o.x = SQRT_EPS - ti * svec.x;
        o.y = SQRT_EPS - ti * svec.y;
        o.z = SQRT_EPS - ti * svec.z;
        o.w = SQRT_EPS - ti * svec.w;
        if (i >= jb && i < jb + 4) {
            const float add = ai - SQRT_EPS;
            if      (i == jb)     o.x += add;
            else if (i == jb + 1) o.y += add;
            else if (i == jb + 2) o.z += add;
            else                  o.w += add;
        }
        Rb[(size_t)i * 64 + j4] = o;
    }
}

extern "C" void kernel_launch(void* const* d_in, const int* in_sizes, int n_in,
                              void* d_out, int out_size, void* d_ws, size_t ws_size,
                              hipStream_t stream) {
    const float* x   = (const float*)d_in[0];
    const float* Wd1 = (const float*)d_in[1];
    const float* bd1 = (const float*)d_in[2];
    const float* Wd2 = (const float*)d_in[3];
    const float* bd2 = (const float*)d_in[4];
    const float* Wu1 = (const float*)d_in[5];
    const float* bu1 = (const float*)d_in[6];
    const float* Wu2 = (const float*)d_in[7];
    const float* bu2 = (const float*)d_in[8];
    const float* Wm1 = (const float*)d_in[9];
    const float* bm1 = (const float*)d_in[10];
    const float* Wm2 = (const float*)d_in[11];
    const float* bm2 = (const float*)d_in[12];
    const float* v   = (const float*)d_in[13];

    float* out      = (float*)d_out;
    float* out_mean = out;                                   // [1024,256]
    float* R        = out + (size_t)NB * N;                  // [1024,256,256]
    float* out_z    = R + (size_t)NB * N * N;                // [1024,256]

    unsigned short* h1g = (unsigned short*)d_ws;             // 3x1024x256 bf16
    float* h2g = (float*)(h1g + (size_t)3 * NBN);            // 3x1024x256 f32

    void* args[] = {
        (void*)&x,
        (void*)&Wd1, (void*)&Wu1, (void*)&Wm1,
        (void*)&Wd2, (void*)&Wu2, (void*)&Wm2,
        (void*)&bd1, (void*)&bu1, (void*)&bm1,
        (void*)&bd2, (void*)&bu2, (void*)&bm2,
        (void*)&h1g, (void*)&h2g
    };
    hipLaunchCooperativeKernel((const void*)coop_mlp_kernel,
                               dim3(256), dim3(768), args, 0, stream);

    r_epi_kernel<<<NB * 4, 256, 0, stream>>>(h2g, v, out_mean, out_z, R);
}

// Round 18
// 64.145 us; speedup vs baseline: 1.5599x; 1.5599x over previous
//
#include <hip/hip_runtime.h>
#include <hip/hip_bf16.h>
#include <math.h>

#define NB 1024
#define N 256
#define NBN (NB * N)
#define EPS 1e-6f
#define SQRT_EPS 1e-3f   // sqrt(1e-6)

typedef short bf16x8 __attribute__((ext_vector_type(8)));
typedef float f32x4  __attribute__((ext_vector_type(4)));

__device__ __forceinline__ float fast_rcp(float x) {
    return __builtin_amdgcn_rcpf(x);
}
__device__ __forceinline__ float sigmoidf(float x) {
    return fast_rcp(1.0f + __expf(-x));
}
__device__ __forceinline__ float fast_tanh(float x) {
    float ax = fabsf(x);
    float e  = __expf(2.0f * ax);
    float t  = 1.0f - 2.0f * fast_rcp(e + 1.0f);
    return copysignf(t, x);
}
__device__ __forceinline__ unsigned short to_bf16(float f) {
    __hip_bfloat16 h = __float2bfloat16(f);
    return *(unsigned short*)&h;
}
__device__ __forceinline__ bf16x8 cvt8(float4 f0, float4 f1) {
    bf16x8 a;
    a[0] = (short)to_bf16(f0.x); a[1] = (short)to_bf16(f0.y);
    a[2] = (short)to_bf16(f0.z); a[3] = (short)to_bf16(f0.w);
    a[4] = (short)to_bf16(f1.x); a[5] = (short)to_bf16(f1.y);
    a[6] = (short)to_bf16(f1.z); a[7] = (short)to_bf16(f1.w);
    return a;
}

// ---- layer 1: 256 blocks (64 rt x 4 ct) x 768 threads (12 waves =
// 3 mlps x 4 subtiles). x staged once -> LDS bf16 (kills 12x redundant
// A loads+cvt). Also converts W2 -> bf16 ws buffer for l2 (1 float4/thread).
// mfma_f32_16x16x32_bf16 frags (verified R12-R17, absmax 0.031):
//   A/B: lane idx = lane&15, k = (lane>>4)*8 + e
//   C/D: col = lane&15 (neuron), row = (lane>>4)*4 + reg (batch row)
__global__ __launch_bounds__(768) void l1_kernel(
    const float* __restrict__ x,
    const float* __restrict__ Wd1, const float* __restrict__ Wu1,
    const float* __restrict__ Wm1,
    const float* __restrict__ Wd2, const float* __restrict__ Wu2,
    const float* __restrict__ Wm2,
    const float* __restrict__ bd1, const float* __restrict__ bu1,
    const float* __restrict__ bm1,
    unsigned short* __restrict__ h1g, unsigned short* __restrict__ Wb2)
{
    __shared__ unsigned short xa[16][264];      // 8.4 KB staged x (bf16)

    const int tid = threadIdx.x;
    const int w   = tid >> 6;          // 0..11
    const int mlp = w >> 2;            // 0..2
    const int sub = w & 3;             // 0..3
    const int l   = tid & 63;
    const int ml  = l & 15;
    const int kg  = l >> 4;
    const int b0  = ((int)blockIdx.x >> 2) * 16;
    const int n0  = ((int)blockIdx.x & 3) * 64 + sub * 16;
    const int n   = n0 + ml;

    // stage x rows -> LDS bf16 (512 threads, one bf16x8 each)
    if (tid < 512) {
        const int row = tid >> 5;
        const int c8  = tid & 31;
        const float* src = x + (size_t)(b0 + row) * N + c8 * 8;
        float4 f0 = *(const float4*)src;
        float4 f1 = *(const float4*)(src + 4);
        *(bf16x8*)&xa[row][c8 * 8] = cvt8(f0, f1);
    }
    __syncthreads();

    bf16x8 af[8];
    #pragma unroll
    for (int kq = 0; kq < 8; ++kq)
        af[kq] = *(const bf16x8*)&xa[ml][kq * 32 + kg * 8];

    const float* Wl = (mlp == 0) ? Wd1 : (mlp == 1) ? Wu1 : Wm1;
    const float* wrow = Wl + (size_t)n * N;
    f32x4 acc = {0.f, 0.f, 0.f, 0.f};
    #pragma unroll
    for (int kq = 0; kq < 8; ++kq) {
        float4 f0 = *(const float4*)(wrow + kq * 32 + kg * 8);
        float4 f1 = *(const float4*)(wrow + kq * 32 + kg * 8 + 4);
        acc = __builtin_amdgcn_mfma_f32_16x16x32_bf16(af[kq], cvt8(f0, f1), acc, 0, 0, 0);
    }
    const float* bias = (mlp == 0) ? bd1 : (mlp == 1) ? bu1 : bm1;
    const float bb = bias[n];
    #pragma unroll
    for (int reg = 0; reg < 4; ++reg) {
        const int row = b0 + kg * 4 + reg;
        float val = acc[reg] + bb;
        float act = (mlp < 2) ? sigmoidf(val) : fast_tanh(val);
        h1g[(size_t)mlp * NBN + (size_t)row * N + n] = to_bf16(act);
    }

    // ---- fold-in: convert W2 (3x65536 f32) -> bf16 for l2 ----
    {
        const int g = (int)blockIdx.x * 768 + tid;     // 0..196607
        if (g < 49152) {                               // 49152 float4s
            const int plane = g >> 14;                 // 0..2
            const int off   = (g & 16383) * 4;
            const float* src = (plane == 0) ? Wd2 : (plane == 1) ? Wu2 : Wm2;
            float4 f = *(const float4*)(src + off);
            ushort4 o;
            o.x = to_bf16(f.x); o.y = to_bf16(f.y);
            o.z = to_bf16(f.z); o.w = to_bf16(f.w);
            *(ushort4*)(Wb2 + plane * 65536 + off) = o;
        }
    }
}

// ---- layer 2: same geometry; A staged from h1g -> LDS; B = prepped bf16
// W2 (direct bf16x8 loads, no cvt). Writes h2g f32 (d,u,m planes).
__global__ __launch_bounds__(768) void l2_kernel(
    const unsigned short* __restrict__ h1g,
    const unsigned short* __restrict__ Wb2,
    const float* __restrict__ bd2, const float* __restrict__ bu2,
    const float* __restrict__ bm2, float* __restrict__ h2g)
{
    __shared__ unsigned short hb[3][16][264];   // 25.3 KB staged h1 (bf16)

    const int tid = threadIdx.x;
    const int w   = tid >> 6;
    const int mlp = w >> 2;
    const int sub = w & 3;
    const int l   = tid & 63;
    const int ml  = l & 15;
    const int kg  = l >> 4;
    const int b0  = ((int)blockIdx.x >> 2) * 16;
    const int n0  = ((int)blockIdx.x & 3) * 64 + sub * 16;
    const int n   = n0 + ml;

    // stage h1 rows (3 planes x 16 rows x 32 chunks = 1536 bf16x8)
    #pragma unroll
    for (int t = 0; t < 2; ++t) {
        const int idx = tid * 2 + t;
        const int m2  = idx >> 9;
        const int rem = idx & 511;
        const int row = rem >> 5;
        const int c8  = rem & 31;
        *(bf16x8*)&hb[m2][row][c8 * 8] =
            *(const bf16x8*)(h1g + (size_t)m2 * NBN + (size_t)(b0 + row) * N + c8 * 8);
    }
    __syncthreads();

    bf16x8 af[8];
    #pragma unroll
    for (int kq = 0; kq < 8; ++kq)
        af[kq] = *(const bf16x8*)&hb[mlp][ml][kq * 32 + kg * 8];

    const unsigned short* wrow = Wb2 + (size_t)mlp * 65536 + (size_t)n * N;
    f32x4 acc = {0.f, 0.f, 0.f, 0.f};
    #pragma unroll
    for (int kq = 0; kq < 8; ++kq) {
        bf16x8 bf = *(const bf16x8*)(wrow + kq * 32 + kg * 8);
        acc = __builtin_amdgcn_mfma_f32_16x16x32_bf16(af[kq], bf, acc, 0, 0, 0);
    }
    const float* bias = (mlp == 0) ? bd2 : (mlp == 1) ? bu2 : bm2;
    const float bb = bias[n];
    #pragma unroll
    for (int reg = 0; reg < 4; ++reg) {
        const int row = b0 + kg * 4 + reg;
        float val = acc[reg] + bb;
        float act = (mlp < 2) ? sigmoidf(val) : fast_tanh(val);
        h2g[(size_t)mlp * NBN + (size_t)row * N + n] = act;
    }
}

// ---- R writer with fused epilogue (BYTE-IDENTICAL to R16's r_epi_kernel).
__global__ __launch_bounds__(256) void r_epi_kernel(
    const float* __restrict__ h2g, const float* __restrict__ v,
    float* __restrict__ out_mean, float* __restrict__ out_z,
    float* __restrict__ R)
{
    __shared__ float s_lds[N];
    __shared__ float a_lds[64];
    __shared__ float tp_lds[64];
    __shared__ float red1[4][3];
    __shared__ float red2[4];

    const int tid   = threadIdx.x;
    const int b     = blockIdx.x >> 2;
    const int chunk = blockIdx.x & 3;
    const int ibase = chunk * 64;
    const int lane  = tid & 63;
    const int wv    = tid >> 6;

    const float d_ = h2g[(size_t)0 * NBN + (size_t)b * N + tid];
    const float u_ = h2g[(size_t)1 * NBN + (size_t)b * N + tid];
    const float m_ = h2g[(size_t)2 * NBN + (size_t)b * N + tid];
    const float vv = v[(size_t)b * N + tid];
    const float inv_d = fast_rcp(d_);

    float s0 = u_, s1 = u_ * u_ * inv_d, s2 = vv;
    #pragma unroll
    for (int off = 32; off > 0; off >>= 1) {
        s0 += __shfl_down(s0, off, 64);
        s1 += __shfl_down(s1, off, 64);
        s2 += __shfl_down(s2, off, 64);
    }
    if (lane == 0) { red1[wv][0] = s0; red1[wv][1] = s1; red1[wv][2] = s2; }
    __syncthreads();
    const float Su = red1[0][0] + red1[1][0] + red1[2][0] + red1[3][0];
    const float qs = red1[0][1] + red1[1][1] + red1[2][1] + red1[3][1];
    const float Sv = red1[0][2] + red1[1][2] + red1[2][2] + red1[3][2];
    const float utDu  = qs + EPS * Su * Su;
    const float sqeta = rsqrtf(1.0f + utDu);
    const float right = (1.0f - sqeta) / utDu;
    const float a  = sqrtf(inv_d + EPS);
    const float s  = u_ * a + SQRT_EPS * (Su - u_);
    const float tp = right * (u_ * inv_d + EPS * Su);

    float sv = s * vv;
    #pragma unroll
    for (int off = 32; off > 0; off >>= 1)
        sv += __shfl_down(sv, off, 64);
    if (lane == 0) red2[wv] = sv;

    s_lds[tid] = s;
    if (tid >= ibase && tid < ibase + 64) {
        a_lds[tid - ibase]  = a;
        tp_lds[tid - ibase] = tp;
    }
    __syncthreads();
    sv = red2[0] + red2[1] + red2[2] + red2[3];

    if (chunk == 0) {
        const size_t idx = (size_t)b * N + tid;
        out_mean[idx] = m_;
        out_z[idx]    = SQRT_EPS * Sv + (a - SQRT_EPS) * vv - tp * sv + m_;
    }

    const int j4 = tid & 63;
    const int il = tid >> 6;
    const float4 svec = ((const float4*)s_lds)[j4];
    float4* Rb = (float4*)(R + (size_t)b * N * N);
    const int jb = j4 * 4;

    #pragma unroll
    for (int it = 0; it < 16; ++it) {
        const int i_loc = it * 4 + il;
        const int i     = ibase + i_loc;
        const float ai  = a_lds[i_loc];
        const float ti  = tp_lds[i_loc];
        float4 o;
        o.x = SQRT_EPS - ti * svec.x;
        o.y = SQRT_EPS - ti * svec.y;
        o.z = SQRT_EPS - ti * svec.z;
        o.w = SQRT_EPS - ti * svec.w;
        if (i >= jb && i < jb + 4) {
            const float add = ai - SQRT_EPS;
            if      (i == jb)     o.x += add;
            else if (i == jb + 1) o.y += add;
            else if (i == jb + 2) o.z += add;
            else                  o.w += add;
        }
        Rb[(size_t)i * 64 + j4] = o;
    }
}

extern "C" void kernel_launch(void* const* d_in, const int* in_sizes, int n_in,
                              void* d_out, int out_size, void* d_ws, size_t ws_size,
                              hipStream_t stream) {
    const float* x   = (const float*)d_in[0];
    const float* Wd1 = (const float*)d_in[1];
    const float* bd1 = (const float*)d_in[2];
    const float* Wd2 = (const float*)d_in[3];
    const float* bd2 = (const float*)d_in[4];
    const float* Wu1 = (const float*)d_in[5];
    const float* bu1 = (const float*)d_in[6];
    const float* Wu2 = (const float*)d_in[7];
    const float* bu2 = (const float*)d_in[8];
    const float* Wm1 = (const float*)d_in[9];
    const float* bm1 = (const float*)d_in[10];
    const float* Wm2 = (const float*)d_in[11];
    const float* bm2 = (const float*)d_in[12];
    const float* v   = (const float*)d_in[13];

    float* out      = (float*)d_out;
    float* out_mean = out;                                   // [1024,256]
    float* R        = out + (size_t)NB * N;                  // [1024,256,256]
    float* out_z    = R + (size_t)NB * N * N;                // [1024,256]

    unsigned short* h1g = (unsigned short*)d_ws;             // 3x1024x256 bf16
    float* h2g = (float*)(h1g + (size_t)3 * NBN);            // 3x1024x256 f32
    unsigned short* Wb2 = (unsigned short*)(h2g + (size_t)3 * NBN);  // 3x65536 bf16

    l1_kernel<<<256, 768, 0, stream>>>(x, Wd1, Wu1, Wm1, Wd2, Wu2, Wm2,
                                       bd1, bu1, bm1, h1g, Wb2);
    l2_kernel<<<256, 768, 0, stream>>>(h1g, Wb2, bd2, bu2, bm2, h2g);
    r_epi_kernel<<<NB * 4, 256, 0, stream>>>(h2g, v, out_mean, out_z, R);
}